// Round 23
// baseline (236.766 us; speedup 1.0000x reference)
//
#include <hip/hip_runtime.h>

#define DEVINL __device__ __forceinline__

typedef __attribute__((ext_vector_type(8))) short bf16x8;
typedef __attribute__((ext_vector_type(4))) float f32x4;
typedef _Float16 half2_t __attribute__((ext_vector_type(2)));
typedef _Float16 f16x8 __attribute__((ext_vector_type(8)));

DEVINL unsigned short f2bf(float f) {
  unsigned int u = __float_as_uint(f);
  u += 0x7FFFu + ((u >> 16) & 1u);
  return (unsigned short)(u >> 16);
}
DEVINL unsigned short f2h(float f) {
  return __builtin_bit_cast(unsigned short, (_Float16)f);
}
DEVINL float sigmf(float x) { return 1.f / (1.f + __expf(-x)); }
DEVINL float tanh_fast(float x) { float e = __expf(2.f * x); return 1.f - 2.f / (e + 1.f); }

DEVINL float fdot2u(unsigned int h, unsigned int w, float acc) {
  return __builtin_amdgcn_fdot2(__builtin_bit_cast(half2_t, h),
                                __builtin_bit_cast(half2_t, w), acc, false);
}

// async 16B global -> LDS (dest must be wave-uniform base; HW adds lane*16)
DEVINL void gload_lds16(const void* g, void* l) {
  __builtin_amdgcn_global_load_lds(
      (const __attribute__((address_space(1))) void*)g,
      (__attribute__((address_space(3))) void*)l, 16, 0, 0);
}

#define FXSCALE 1048576.f        // 2^20
#define FXINV   (1.f / 1048576.f)

// ---------------- fused prologue, INTERLEAVED ranges for co-scheduling ----------------
// even blk<1536 -> gcn (768) | odd blk<1536 -> conv_bf16 (768) | 1536..1767 conv_bf16
// (232 more) | 1768..1895 packs | 1896..2151 conv_f16
__global__ __launch_bounds__(1024) void fused_pre(
    const float* __restrict__ x, const int* __restrict__ ei, const float* __restrict__ ed,
    const float* __restrict__ Wg, const float* __restrict__ bg,
    unsigned short* __restrict__ G,
    const float* __restrict__ Wih0, unsigned short* __restrict__ W0bf,
    const float* __restrict__ Whh0, uint2* __restrict__ WPG0,
    const float* __restrict__ Whh1, uint2* __restrict__ WPG1,
    const float* __restrict__ Wih1, unsigned short* __restrict__ W1h) {
  __shared__ float xs[2000];
  __shared__ int Ai[2000];
  __shared__ int Di[2000];
  int blk = blockIdx.x;
  int tid = threadIdx.x;

  if (blk < 1536 && (blk & 1) == 0) {
    // ---- GCN graph aggregation (even blocks: interleaved with conv for co-residency) ----
    int bs = blk >> 1;
    for (int i = tid; i < 2000; i += 1024) {
      xs[i] = x[(size_t)bs * 2000 + i];
      Ai[i] = 0; Di[i] = 0;
    }
    bool bgz = (bg[0] == 0.f) && (bg[1] == 0.f) && (bg[2] == 0.f) && (bg[3] == 0.f) &&
               (bg[4] == 0.f) && (bg[5] == 0.f) && (bg[6] == 0.f) && (bg[7] == 0.f);
    __syncthreads();
    const int4* srcp = (const int4*)(ei + (size_t)bs * 32000);
    const int4* dstp = (const int4*)(ei + (size_t)bs * 32000 + 16000);
    const float4* dp = (const float4*)(ed + (size_t)bs * 16000);
    if (bgz) {
      for (int i = tid; i < 4000; i += 1024) {
        int4 s4 = srcp[i];
        int4 d4 = dstp[i];
        float4 w4 = dp[i];
        atomicAdd(&Ai[d4.x], __float2int_rn(w4.x * xs[s4.x] * FXSCALE));
        atomicAdd(&Ai[d4.y], __float2int_rn(w4.y * xs[s4.y] * FXSCALE));
        atomicAdd(&Ai[d4.z], __float2int_rn(w4.z * xs[s4.z] * FXSCALE));
        atomicAdd(&Ai[d4.w], __float2int_rn(w4.w * xs[s4.w] * FXSCALE));
      }
    } else {
      for (int i = tid; i < 4000; i += 1024) {
        int4 s4 = srcp[i];
        int4 d4 = dstp[i];
        float4 w4 = dp[i];
        atomicAdd(&Ai[d4.x], __float2int_rn(w4.x * xs[s4.x] * FXSCALE));
        atomicAdd(&Di[d4.x], __float2int_rn(w4.x * FXSCALE));
        atomicAdd(&Ai[d4.y], __float2int_rn(w4.y * xs[s4.y] * FXSCALE));
        atomicAdd(&Di[d4.y], __float2int_rn(w4.y * FXSCALE));
        atomicAdd(&Ai[d4.z], __float2int_rn(w4.z * xs[s4.z] * FXSCALE));
        atomicAdd(&Di[d4.z], __float2int_rn(w4.z * FXSCALE));
        atomicAdd(&Ai[d4.w], __float2int_rn(w4.w * xs[s4.w] * FXSCALE));
        atomicAdd(&Di[d4.w], __float2int_rn(w4.w * FXSCALE));
      }
    }
    __syncthreads();
    float wreg[8], breg[8];
#pragma unroll
    for (int f = 0; f < 8; ++f) { wreg[f] = Wg[f]; breg[f] = bg[f]; }
    for (int n = tid; n < 2000; n += 1024) {
      float a  = (float)Ai[n] * FXINV;
      float dd = (float)Di[n] * FXINV;
      unsigned int u[4];
#pragma unroll
      for (int p = 0; p < 4; ++p) {
        float v0 = tanh_fast(wreg[2 * p] * a + breg[2 * p] * dd);
        float v1 = tanh_fast(wreg[2 * p + 1] * a + breg[2 * p + 1] * dd);
        u[p] = (unsigned int)f2bf(v0) | ((unsigned int)f2bf(v1) << 16);
      }
      *(uint4*)&G[(size_t)bs * 16000 + n * 8] = make_uint4(u[0], u[1], u[2], u[3]);
    }
  } else if (blk < 1768) {
    // ---- conv_bf16: Wih0 f32 -> bf16; job j in 0..999 ----
    int j = (blk < 1536) ? (blk >> 1) : (768 + (blk - 1536));
    int base = j * 1024 + tid;
#pragma unroll
    for (int k = 0; k < 4; ++k) {
      int id = base + k * 1024000;
      float4 v = *(const float4*)&Wih0[(size_t)id * 4];
      unsigned int a = (unsigned int)f2bf(v.x) | ((unsigned int)f2bf(v.y) << 16);
      unsigned int b = (unsigned int)f2bf(v.z) | ((unsigned int)f2bf(v.w) << 16);
      *(uint2*)&W0bf[(size_t)id * 4] = make_uint2(a, b);
    }
  } else if (blk < 1896) {
    // ---- pack_whh: [4 groups][64 u2][256 c] f16 pairs (65,536 items each) ----
    const float* in = (blk < 1832) ? Whh0 : Whh1;
    uint2* outp = (blk < 1832) ? WPG0 : WPG1;
    int id = ((blk < 1832) ? (blk - 1768) : (blk - 1832)) * 1024 + tid;
    int g = id >> 14;
    int rem = id & 16383;
    int u2 = rem >> 8;
    int c = rem & 255;
    int col = (c >> 6) * 256 + g * 64 + (c & 63);
    float4 v = *(const float4*)&in[col * 256 + u2 * 4];
    unsigned int p0 = (unsigned int)f2h(v.x) | ((unsigned int)f2h(v.y) << 16);
    unsigned int p1 = (unsigned int)f2h(v.z) | ((unsigned int)f2h(v.w) << 16);
    outp[id] = make_uint2(p0, p1);
  } else {
    // ---- conv_f16: Wih1 f32 -> f16 (262,144 elems) ----
    int id = (blk - 1896) * 1024 + tid;
    W1h[id] = f2h(Wih1[id]);
  }
}

// ---------------- big MFMA GEMM: counted-vmcnt double-buffered pipeline ----------------
__global__ __launch_bounds__(256) void gemm_bt(
    const unsigned short* __restrict__ A, const unsigned short* __restrict__ B,
    float* __restrict__ Cp) {
  __shared__ __align__(16) unsigned short As[2][128 * 32];
  __shared__ __align__(16) unsigned short Bs[2][128 * 32];
  const int K = 16000;
  int nt = blockIdx.x;
  int mt = blockIdx.y;
  int ks = blockIdx.z;
  int m0 = mt * 128, n0 = nt * 128;
  int tid = threadIdx.x;
  int lane = tid & 63;
  int w = tid >> 6;
  int wm = (w >> 1) * 64, wn = (w & 1) * 64;
  int fr = lane & 15;
  int kg = lane >> 4;

  f32x4 acc[4][4] = {};
  const unsigned short* Ag = A + (size_t)m0 * K + ks * 1600;
  const unsigned short* Bg = B + (size_t)n0 * K + ks * 1600;

  int row0 = tid >> 2,            ko0 = (tid & 3) * 8,        cb0 = (tid & ~63);
  int row1 = (256 + tid) >> 2,    ko1 = (tid & 3) * 8,        cb1 = 256 + (tid & ~63);

#define STAGE_BT(buf, kk)                                                     \
  do {                                                                        \
    gload_lds16(&Ag[(size_t)row0 * K + (kk) + ko0], &As[buf][cb0 * 8]);       \
    gload_lds16(&Bg[(size_t)row0 * K + (kk) + ko0], &Bs[buf][cb0 * 8]);       \
    gload_lds16(&Ag[(size_t)row1 * K + (kk) + ko1], &As[buf][cb1 * 8]);       \
    gload_lds16(&Bg[(size_t)row1 * K + (kk) + ko1], &Bs[buf][cb1 * 8]);       \
  } while (0)

  STAGE_BT(0, 0);
#pragma unroll 1
  for (int it = 0; it < 50; ++it) {
    int cur = it & 1;
    if (it < 49) {
      STAGE_BT(cur ^ 1, (it + 1) * 32);
      asm volatile("s_waitcnt vmcnt(4)" ::: "memory");
    } else {
      asm volatile("s_waitcnt vmcnt(0)" ::: "memory");
    }
    __builtin_amdgcn_s_barrier();
    __builtin_amdgcn_sched_barrier(0);
    bf16x8 aF[4], bF[4];
#pragma unroll
    for (int i = 0; i < 4; ++i)
      aF[i] = *(const bf16x8*)&As[cur][(wm + i * 16 + fr) * 32 + kg * 8];
#pragma unroll
    for (int i = 0; i < 4; ++i)
      bF[i] = *(const bf16x8*)&Bs[cur][(wn + i * 16 + fr) * 32 + kg * 8];
#pragma unroll
    for (int i = 0; i < 4; ++i)
#pragma unroll
      for (int j = 0; j < 4; ++j)
        acc[i][j] = __builtin_amdgcn_mfma_f32_16x16x32_bf16(aF[i], bF[j], acc[i][j], 0, 0, 0);
    __builtin_amdgcn_s_barrier();
  }
#undef STAGE_BT
  float* Co = Cp + (size_t)ks * 768 * 1024;
  int mr = (lane >> 4) * 4;
#pragma unroll
  for (int i = 0; i < 4; ++i)
#pragma unroll
    for (int j = 0; j < 4; ++j) {
      int n = n0 + wn + j * 16 + fr;
#pragma unroll
      for (int r = 0; r < 4; ++r) {
        int m = m0 + wm + i * 16 + mr + r;
        Co[(size_t)m * 1024 + n] = acc[i][j][r];
      }
    }
}

// ---------------- LSTM: 4 blocks/batch co-located per XCD, tag-embedded h-exchange ----
// If Cp != nullptr: gate preactivation computed inline from 10 split-K partials + bias
// (fuses reduce_z0). Else: read Z directly.
__global__ __launch_bounds__(1024) void lstm_sync2(
    const float* __restrict__ Z, const float* __restrict__ Cp,
    const float* __restrict__ bih, const float* __restrict__ bhh,
    const uint2* __restrict__ WPG,
    unsigned int* __restrict__ Hex, unsigned short* __restrict__ Hout,
    float* __restrict__ lastOut, int tagBase) {
  __shared__ __align__(16) uint2 Wl2[64 * 256];    // 131,072 B
  __shared__ float gparts[1024];                   // 4 KB
  __shared__ __align__(8) unsigned short h16[256]; // 512 B
  int bid = blockIdx.x;
  int b = bid & 31, g = bid >> 5;   // XCD co-locating decomposition
  int tid = threadIdx.x;
  int lane = tid & 63;
  int c = tid & 255;
  int kh = __builtin_amdgcn_readfirstlane(tid >> 8);   // K-quarter 0..3
  int q = c >> 6, r = c & 63;
  int col = q * 256 + g * 64 + r;

  const uint2* wsrc = WPG + (size_t)g * 16384;
  for (int i = tid; i < 16384; i += 1024) Wl2[i] = wsrc[i];
  if (tid < 128) ((unsigned int*)h16)[tid] = 0;
  float biasc = (Cp != nullptr && kh == 0) ? (bih[col] + bhh[col]) : 0.f;
  __syncthreads();

  float cst = 0.f;
  const size_t b24 = (size_t)b * 24;

#pragma unroll 1
  for (int t = 0; t < 24; ++t) {
    uint2 hv = *(const uint2*)&((const unsigned int*)h16)[lane * 2];
    // gate preactivation (kh==0 lanes): fused split-K reduce or direct read
    float z = 0.f;
    if (kh == 0) {
      if (Cp != nullptr) {
        size_t off = (b24 + t) * 1024 + col;
        float s = biasc;
#pragma unroll
        for (int p = 0; p < 10; ++p) s += Cp[(size_t)p * 786432 + off];
        z = s;
      } else {
        z = Z[(b24 + t) * 1024 + col];
      }
    }
    float acc = 0.f;
#pragma unroll
    for (int j = 0; j < 16; ++j) {
      const int u2i = kh * 16 + j;
      uint2 w2 = Wl2[u2i * 256 + c];
      unsigned int h0 = (unsigned int)__builtin_amdgcn_readlane((int)hv.x, u2i);
      unsigned int h1 = (unsigned int)__builtin_amdgcn_readlane((int)hv.y, u2i);
      acc = fdot2u(h0, w2.x, acc);
      acc = fdot2u(h1, w2.y, acc);
    }
    gparts[tid] = acc + z;
    __syncthreads();
    unsigned int* HexS = Hex + (t & 1) * 8192 + b * 256;
    if (tid < 64) {
      float i_ = gparts[tid]       + gparts[tid + 256]  + gparts[tid + 512]  + gparts[tid + 768];
      float f_ = gparts[tid + 64]  + gparts[tid + 320]  + gparts[tid + 576]  + gparts[tid + 832];
      float g_ = gparts[tid + 128] + gparts[tid + 384]  + gparts[tid + 640]  + gparts[tid + 896];
      float o_ = gparts[tid + 192] + gparts[tid + 448]  + gparts[tid + 704]  + gparts[tid + 960];
      float ig = sigmf(i_), fg = sigmf(f_);
      float gg = tanh_fast(g_), og = sigmf(o_);
      cst = fg * cst + ig * gg;
      float h = og * tanh_fast(cst);
      unsigned short hh = f2h(h);
      h16[g * 64 + tid] = hh;
      __hip_atomic_store(&HexS[g * 64 + tid],
                         (unsigned int)hh | ((unsigned int)(tagBase + t + 1) << 16),
                         __ATOMIC_RELAXED, __HIP_MEMORY_SCOPE_AGENT);
      if (Hout) Hout[(b24 + t) * 256 + g * 64 + tid] = hh;
      if (lastOut && t == 23) lastOut[b * 256 + g * 64 + tid] = tanh_fast(h);
    }
    if (t == 23) break;
    if (tid < 256 && (tid >> 6) != g) {
      const unsigned int tag = (unsigned int)(tagBase + t + 1);
      unsigned int v;
      do {
        v = __hip_atomic_load(&HexS[tid], __ATOMIC_RELAXED, __HIP_MEMORY_SCOPE_AGENT);
      } while ((v >> 16) != tag);
      h16[tid] = (unsigned short)(v & 0xFFFFu);
    }
    __syncthreads();
  }
}

// ---------------- Z1 = H1f16 @ Wih1f16^T + biases (MFMA) ----------------
__global__ __launch_bounds__(256) void gemm_z1_mfma(
    const unsigned short* __restrict__ A, const unsigned short* __restrict__ B,
    const float* __restrict__ bih, const float* __restrict__ bhh,
    float* __restrict__ Z1) {
  __shared__ __align__(16) unsigned short As[128 * 32];
  __shared__ __align__(16) unsigned short Bs[128 * 32];
  const int K = 256;
  int nt = blockIdx.x;   // 0..7
  int mt = blockIdx.y;   // 0..5
  int m0 = mt * 128, n0 = nt * 128;
  int tid = threadIdx.x;
  int lane = tid & 63;
  int w = tid >> 6;
  int wm = (w >> 1) * 64, wn = (w & 1) * 64;
  int fr = lane & 15;
  int kg = lane >> 4;

  f32x4 acc[4][4] = {};
  const unsigned short* Ag = A + (size_t)m0 * K;
  const unsigned short* Bg = B + (size_t)n0 * K;

  for (int kk = 0; kk < 256; kk += 32) {
#pragma unroll
    for (int q = 0; q < 2; ++q) {
      int c = q * 256 + tid;
      int row = c >> 2;
      int ko = (c & 3) * 8;
      int cb = q * 256 + (tid & ~63);
      gload_lds16(&Ag[(size_t)row * K + kk + ko], &As[cb * 8]);
      gload_lds16(&Bg[(size_t)row * K + kk + ko], &Bs[cb * 8]);
    }
    __syncthreads();
    f16x8 aF[4], bF[4];
#pragma unroll
    for (int i = 0; i < 4; ++i)
      aF[i] = *(const f16x8*)&As[(wm + i * 16 + fr) * 32 + kg * 8];
#pragma unroll
    for (int i = 0; i < 4; ++i)
      bF[i] = *(const f16x8*)&Bs[(wn + i * 16 + fr) * 32 + kg * 8];
#pragma unroll
    for (int i = 0; i < 4; ++i)
#pragma unroll
      for (int j = 0; j < 4; ++j)
        acc[i][j] = __builtin_amdgcn_mfma_f32_16x16x32_f16(aF[i], bF[j], acc[i][j], 0, 0, 0);
    __syncthreads();
  }
  int mr = (lane >> 4) * 4;
#pragma unroll
  for (int j = 0; j < 4; ++j) {
    int n = n0 + wn + j * 16 + fr;
    float bias = bih[n] + bhh[n];
#pragma unroll
    for (int i = 0; i < 4; ++i) {
#pragma unroll
      for (int r = 0; r < 4; ++r) {
        int m = m0 + wm + i * 16 + mr + r;
        Z1[(size_t)m * 1024 + n] = acc[i][j][r] + bias;
      }
    }
  }
}

// ---------------- fc: out = last @ fc_W^T + fc_b ----------------
__global__ __launch_bounds__(256) void fc_kernel(
    const float* __restrict__ last, const float* __restrict__ fcW,
    const float* __restrict__ fcb, float* __restrict__ out) {
  __shared__ float ls[8][256];
  int tid = threadIdx.x;
  int o = blockIdx.x * 256 + tid;
  int b0 = blockIdx.y * 8;
  for (int i = tid; i < 2048; i += 256)
    ls[i >> 8][i & 255] = last[(b0 + (i >> 8)) * 256 + (i & 255)];
  __syncthreads();
  if (o < 8000) {
    float acc[8] = {};
    for (int k = 0; k < 256; k += 4) {
      float4 wv = *(const float4*)&fcW[(size_t)o * 256 + k];
#pragma unroll
      for (int b = 0; b < 8; ++b)
        acc[b] += wv.x * ls[b][k] + wv.y * ls[b][k + 1] + wv.z * ls[b][k + 2] + wv.w * ls[b][k + 3];
    }
    float bias = fcb[o];
#pragma unroll
    for (int b = 0; b < 8; ++b) out[(size_t)(b0 + b) * 8000 + o] = acc[b] + bias;
  }
}

// ---------------- launch ----------------
extern "C" void kernel_launch(void* const* d_in, const int* in_sizes, int n_in,
                              void* d_out, int out_size, void* d_ws, size_t ws_size,
                              hipStream_t stream) {
  const float* x    = (const float*)d_in[0];
  const int*   ei   = (const int*)d_in[1];
  const float* ed   = (const float*)d_in[2];
  const float* Wg   = (const float*)d_in[3];
  const float* bg   = (const float*)d_in[4];
  const float* Wih0 = (const float*)d_in[5];
  const float* Whh0 = (const float*)d_in[6];
  const float* bih0 = (const float*)d_in[7];
  const float* bhh0 = (const float*)d_in[8];
  const float* Wih1 = (const float*)d_in[9];
  const float* Whh1 = (const float*)d_in[10];
  const float* bih1 = (const float*)d_in[11];
  const float* bhh1 = (const float*)d_in[12];
  const float* fcW  = (const float*)d_in[13];
  const float* fcb  = (const float*)d_in[14];
  float* out = (float*)d_out;

  char* ws = (char*)d_ws;
  unsigned short* Gbf  = (unsigned short*)(ws);              // 24,576,000
  unsigned short* W0bf = (unsigned short*)(ws + 24576000);   // 32,768,000
  float* Zpart = (float*)(ws + 57344000);                    // 31,457,280
  uint2* WPG0  = (uint2*)(ws + 91947008);                    //    524,288
  uint2* WPG1  = (uint2*)(ws + 92471296);                    //    524,288
  unsigned short* W1h = (unsigned short*)(ws + 92995584);    //    524,288 (f16 Wih1)
  unsigned short* H1  = (unsigned short*)(ws + 94044160);    //    393,216 (f16 H1)
  float* Z1    = (float*)(ws + 94830592);                    //  3,145,728
  float* lastb = (float*)(ws + 97976320);                    //     32,768
  unsigned int* Hex0 = (unsigned int*)(ws + 98009088);       //     65,536
  unsigned int* Hex1 = (unsigned int*)(ws + 98074624);       //     65,536  (end ~98.1 MB)

  hipMemsetAsync(Hex0, 0, 131072, stream);   // zero both Hex buffers (tags invalid)
  fused_pre<<<2152, 1024, 0, stream>>>(x, ei, ed, Wg, bg, Gbf,
                                       Wih0, W0bf, Whh0, WPG0, Whh1, WPG1,
                                       Wih1, (unsigned short*)W1h);
  gemm_bt<<<dim3(8, 6, 10), 256, 0, stream>>>(Gbf, W0bf, Zpart);
  lstm_sync2<<<128, 1024, 0, stream>>>(nullptr, Zpart, bih0, bhh0, WPG0,
                                       Hex0, H1, nullptr, 0);
  gemm_z1_mfma<<<dim3(8, 6), 256, 0, stream>>>(H1, W1h, bih1, bhh1, Z1);
  lstm_sync2<<<128, 1024, 0, stream>>>(Z1, nullptr, nullptr, nullptr, WPG1,
                                       Hex1, nullptr, lastb, 100);
  fc_kernel<<<dim3(32, 4), 256, 0, stream>>>(lastb, fcW, fcb, out);
}

// Round 24
// 231.238 us; speedup vs baseline: 1.0239x; 1.0239x over previous
//
#include <hip/hip_runtime.h>

#define DEVINL __device__ __forceinline__

typedef __attribute__((ext_vector_type(8))) short bf16x8;
typedef __attribute__((ext_vector_type(4))) float f32x4;
typedef _Float16 half2_t __attribute__((ext_vector_type(2)));
typedef _Float16 f16x8 __attribute__((ext_vector_type(8)));

DEVINL unsigned short f2bf(float f) {
  unsigned int u = __float_as_uint(f);
  u += 0x7FFFu + ((u >> 16) & 1u);
  return (unsigned short)(u >> 16);
}
DEVINL unsigned short f2h(float f) {
  return __builtin_bit_cast(unsigned short, (_Float16)f);
}
DEVINL float sigmf(float x) { return 1.f / (1.f + __expf(-x)); }
DEVINL float tanh_fast(float x) { float e = __expf(2.f * x); return 1.f - 2.f / (e + 1.f); }

DEVINL float fdot2u(unsigned int h, unsigned int w, float acc) {
  return __builtin_amdgcn_fdot2(__builtin_bit_cast(half2_t, h),
                                __builtin_bit_cast(half2_t, w), acc, false);
}

// async 16B global -> LDS (dest must be wave-uniform base; HW adds lane*16)
DEVINL void gload_lds16(const void* g, void* l) {
  __builtin_amdgcn_global_load_lds(
      (const __attribute__((address_space(1))) void*)g,
      (__attribute__((address_space(3))) void*)l, 16, 0, 0);
}

#define FXSCALE 1048576.f        // 2^20
#define FXINV   (1.f / 1048576.f)

// ---------------- fused prologue, CONTIGUOUS ranges (round-22 mapping) ----------------
// gcn (0..767) | conv_bf16 (768..1767) | packs (1768..1895) | conv_f16 (1896..2151)
__global__ __launch_bounds__(1024) void fused_pre(
    const float* __restrict__ x, const int* __restrict__ ei, const float* __restrict__ ed,
    const float* __restrict__ Wg, const float* __restrict__ bg,
    unsigned short* __restrict__ G,
    const float* __restrict__ Wih0, unsigned short* __restrict__ W0bf,
    const float* __restrict__ Whh0, uint2* __restrict__ WPG0,
    const float* __restrict__ Whh1, uint2* __restrict__ WPG1,
    const float* __restrict__ Wih1, unsigned short* __restrict__ W1h) {
  __shared__ float xs[2000];
  __shared__ int Ai[2000];
  __shared__ int Di[2000];
  int blk = blockIdx.x;
  int tid = threadIdx.x;

  if (blk < 768) {
    // ---- GCN graph aggregation ----
    int bs = blk;
    for (int i = tid; i < 2000; i += 1024) {
      xs[i] = x[(size_t)bs * 2000 + i];
      Ai[i] = 0; Di[i] = 0;
    }
    bool bgz = (bg[0] == 0.f) && (bg[1] == 0.f) && (bg[2] == 0.f) && (bg[3] == 0.f) &&
               (bg[4] == 0.f) && (bg[5] == 0.f) && (bg[6] == 0.f) && (bg[7] == 0.f);
    __syncthreads();
    const int4* srcp = (const int4*)(ei + (size_t)bs * 32000);
    const int4* dstp = (const int4*)(ei + (size_t)bs * 32000 + 16000);
    const float4* dp = (const float4*)(ed + (size_t)bs * 16000);
    if (bgz) {
      for (int i = tid; i < 4000; i += 1024) {
        int4 s4 = srcp[i];
        int4 d4 = dstp[i];
        float4 w4 = dp[i];
        atomicAdd(&Ai[d4.x], __float2int_rn(w4.x * xs[s4.x] * FXSCALE));
        atomicAdd(&Ai[d4.y], __float2int_rn(w4.y * xs[s4.y] * FXSCALE));
        atomicAdd(&Ai[d4.z], __float2int_rn(w4.z * xs[s4.z] * FXSCALE));
        atomicAdd(&Ai[d4.w], __float2int_rn(w4.w * xs[s4.w] * FXSCALE));
      }
    } else {
      for (int i = tid; i < 4000; i += 1024) {
        int4 s4 = srcp[i];
        int4 d4 = dstp[i];
        float4 w4 = dp[i];
        atomicAdd(&Ai[d4.x], __float2int_rn(w4.x * xs[s4.x] * FXSCALE));
        atomicAdd(&Di[d4.x], __float2int_rn(w4.x * FXSCALE));
        atomicAdd(&Ai[d4.y], __float2int_rn(w4.y * xs[s4.y] * FXSCALE));
        atomicAdd(&Di[d4.y], __float2int_rn(w4.y * FXSCALE));
        atomicAdd(&Ai[d4.z], __float2int_rn(w4.z * xs[s4.z] * FXSCALE));
        atomicAdd(&Di[d4.z], __float2int_rn(w4.z * FXSCALE));
        atomicAdd(&Ai[d4.w], __float2int_rn(w4.w * xs[s4.w] * FXSCALE));
        atomicAdd(&Di[d4.w], __float2int_rn(w4.w * FXSCALE));
      }
    }
    __syncthreads();
    float wreg[8], breg[8];
#pragma unroll
    for (int f = 0; f < 8; ++f) { wreg[f] = Wg[f]; breg[f] = bg[f]; }
    for (int n = tid; n < 2000; n += 1024) {
      float a  = (float)Ai[n] * FXINV;
      float dd = (float)Di[n] * FXINV;
      unsigned int u[4];
#pragma unroll
      for (int p = 0; p < 4; ++p) {
        float v0 = tanh_fast(wreg[2 * p] * a + breg[2 * p] * dd);
        float v1 = tanh_fast(wreg[2 * p + 1] * a + breg[2 * p + 1] * dd);
        u[p] = (unsigned int)f2bf(v0) | ((unsigned int)f2bf(v1) << 16);
      }
      *(uint4*)&G[(size_t)bs * 16000 + n * 8] = make_uint4(u[0], u[1], u[2], u[3]);
    }
  } else if (blk < 1768) {
    // ---- conv_bf16: Wih0 f32 -> bf16, 4,096,000 float4-groups ----
    int base = (blk - 768) * 1024 + tid;
#pragma unroll
    for (int k = 0; k < 4; ++k) {
      int id = base + k * 1024000;
      float4 v = *(const float4*)&Wih0[(size_t)id * 4];
      unsigned int a = (unsigned int)f2bf(v.x) | ((unsigned int)f2bf(v.y) << 16);
      unsigned int b = (unsigned int)f2bf(v.z) | ((unsigned int)f2bf(v.w) << 16);
      *(uint2*)&W0bf[(size_t)id * 4] = make_uint2(a, b);
    }
  } else if (blk < 1896) {
    // ---- pack_whh: [4 groups][64 u2][256 c] f16 pairs (65,536 items each) ----
    const float* in = (blk < 1832) ? Whh0 : Whh1;
    uint2* outp = (blk < 1832) ? WPG0 : WPG1;
    int id = ((blk < 1832) ? (blk - 1768) : (blk - 1832)) * 1024 + tid;
    int g = id >> 14;
    int rem = id & 16383;
    int u2 = rem >> 8;
    int c = rem & 255;
    int col = (c >> 6) * 256 + g * 64 + (c & 63);
    float4 v = *(const float4*)&in[col * 256 + u2 * 4];
    unsigned int p0 = (unsigned int)f2h(v.x) | ((unsigned int)f2h(v.y) << 16);
    unsigned int p1 = (unsigned int)f2h(v.z) | ((unsigned int)f2h(v.w) << 16);
    outp[id] = make_uint2(p0, p1);
  } else {
    // ---- conv_f16: Wih1 f32 -> f16 (262,144 elems) ----
    int id = (blk - 1896) * 1024 + tid;
    W1h[id] = f2h(Wih1[id]);
  }
}

// ---------------- big MFMA GEMM: counted-vmcnt double-buffered pipeline ----------------
__global__ __launch_bounds__(256) void gemm_bt(
    const unsigned short* __restrict__ A, const unsigned short* __restrict__ B,
    float* __restrict__ Cp) {
  __shared__ __align__(16) unsigned short As[2][128 * 32];
  __shared__ __align__(16) unsigned short Bs[2][128 * 32];
  const int K = 16000;
  int nt = blockIdx.x;
  int mt = blockIdx.y;
  int ks = blockIdx.z;
  int m0 = mt * 128, n0 = nt * 128;
  int tid = threadIdx.x;
  int lane = tid & 63;
  int w = tid >> 6;
  int wm = (w >> 1) * 64, wn = (w & 1) * 64;
  int fr = lane & 15;
  int kg = lane >> 4;

  f32x4 acc[4][4] = {};
  const unsigned short* Ag = A + (size_t)m0 * K + ks * 1600;
  const unsigned short* Bg = B + (size_t)n0 * K + ks * 1600;

  int row0 = tid >> 2,            ko0 = (tid & 3) * 8,        cb0 = (tid & ~63);
  int row1 = (256 + tid) >> 2,    ko1 = (tid & 3) * 8,        cb1 = 256 + (tid & ~63);

#define STAGE_BT(buf, kk)                                                     \
  do {                                                                        \
    gload_lds16(&Ag[(size_t)row0 * K + (kk) + ko0], &As[buf][cb0 * 8]);       \
    gload_lds16(&Bg[(size_t)row0 * K + (kk) + ko0], &Bs[buf][cb0 * 8]);       \
    gload_lds16(&Ag[(size_t)row1 * K + (kk) + ko1], &As[buf][cb1 * 8]);       \
    gload_lds16(&Bg[(size_t)row1 * K + (kk) + ko1], &Bs[buf][cb1 * 8]);       \
  } while (0)

  STAGE_BT(0, 0);
#pragma unroll 1
  for (int it = 0; it < 50; ++it) {
    int cur = it & 1;
    if (it < 49) {
      STAGE_BT(cur ^ 1, (it + 1) * 32);
      asm volatile("s_waitcnt vmcnt(4)" ::: "memory");
    } else {
      asm volatile("s_waitcnt vmcnt(0)" ::: "memory");
    }
    __builtin_amdgcn_s_barrier();
    __builtin_amdgcn_sched_barrier(0);
    bf16x8 aF[4], bF[4];
#pragma unroll
    for (int i = 0; i < 4; ++i)
      aF[i] = *(const bf16x8*)&As[cur][(wm + i * 16 + fr) * 32 + kg * 8];
#pragma unroll
    for (int i = 0; i < 4; ++i)
      bF[i] = *(const bf16x8*)&Bs[cur][(wn + i * 16 + fr) * 32 + kg * 8];
#pragma unroll
    for (int i = 0; i < 4; ++i)
#pragma unroll
      for (int j = 0; j < 4; ++j)
        acc[i][j] = __builtin_amdgcn_mfma_f32_16x16x32_bf16(aF[i], bF[j], acc[i][j], 0, 0, 0);
    __builtin_amdgcn_s_barrier();
  }
#undef STAGE_BT
  float* Co = Cp + (size_t)ks * 768 * 1024;
  int mr = (lane >> 4) * 4;
#pragma unroll
  for (int i = 0; i < 4; ++i)
#pragma unroll
    for (int j = 0; j < 4; ++j) {
      int n = n0 + wn + j * 16 + fr;
#pragma unroll
      for (int r = 0; r < 4; ++r) {
        int m = m0 + wm + i * 16 + mr + r;
        Co[(size_t)m * 1024 + n] = acc[i][j][r];
      }
    }
}

// ---------------- LSTM: 4 blocks/batch co-located per XCD, tag-embedded h-exchange ----
// If Cp != nullptr: gate preactivation computed inline from 10 split-K partials + bias
// (fuses reduce_z0). Else: read Z directly.
__global__ __launch_bounds__(1024) void lstm_sync2(
    const float* __restrict__ Z, const float* __restrict__ Cp,
    const float* __restrict__ bih, const float* __restrict__ bhh,
    const uint2* __restrict__ WPG,
    unsigned int* __restrict__ Hex, unsigned short* __restrict__ Hout,
    float* __restrict__ lastOut, int tagBase) {
  __shared__ __align__(16) uint2 Wl2[64 * 256];    // 131,072 B
  __shared__ float gparts[1024];                   // 4 KB
  __shared__ __align__(8) unsigned short h16[256]; // 512 B
  int bid = blockIdx.x;
  int b = bid & 31, g = bid >> 5;   // XCD co-locating decomposition
  int tid = threadIdx.x;
  int lane = tid & 63;
  int c = tid & 255;
  int kh = __builtin_amdgcn_readfirstlane(tid >> 8);   // K-quarter 0..3
  int q = c >> 6, r = c & 63;
  int col = q * 256 + g * 64 + r;

  const uint2* wsrc = WPG + (size_t)g * 16384;
  for (int i = tid; i < 16384; i += 1024) Wl2[i] = wsrc[i];
  if (tid < 128) ((unsigned int*)h16)[tid] = 0;
  float biasc = (Cp != nullptr && kh == 0) ? (bih[col] + bhh[col]) : 0.f;
  __syncthreads();

  float cst = 0.f;
  const size_t b24 = (size_t)b * 24;

#pragma unroll 1
  for (int t = 0; t < 24; ++t) {
    uint2 hv = *(const uint2*)&((const unsigned int*)h16)[lane * 2];
    float z = 0.f;
    if (kh == 0) {
      if (Cp != nullptr) {
        size_t off = (b24 + t) * 1024 + col;
        float s = biasc;
#pragma unroll
        for (int p = 0; p < 10; ++p) s += Cp[(size_t)p * 786432 + off];
        z = s;
      } else {
        z = Z[(b24 + t) * 1024 + col];
      }
    }
    float acc = 0.f;
#pragma unroll
    for (int j = 0; j < 16; ++j) {
      const int u2i = kh * 16 + j;
      uint2 w2 = Wl2[u2i * 256 + c];
      unsigned int h0 = (unsigned int)__builtin_amdgcn_readlane((int)hv.x, u2i);
      unsigned int h1 = (unsigned int)__builtin_amdgcn_readlane((int)hv.y, u2i);
      acc = fdot2u(h0, w2.x, acc);
      acc = fdot2u(h1, w2.y, acc);
    }
    gparts[tid] = acc + z;
    __syncthreads();
    unsigned int* HexS = Hex + (t & 1) * 8192 + b * 256;
    if (tid < 64) {
      float i_ = gparts[tid]       + gparts[tid + 256]  + gparts[tid + 512]  + gparts[tid + 768];
      float f_ = gparts[tid + 64]  + gparts[tid + 320]  + gparts[tid + 576]  + gparts[tid + 832];
      float g_ = gparts[tid + 128] + gparts[tid + 384]  + gparts[tid + 640]  + gparts[tid + 896];
      float o_ = gparts[tid + 192] + gparts[tid + 448]  + gparts[tid + 704]  + gparts[tid + 960];
      float ig = sigmf(i_), fg = sigmf(f_);
      float gg = tanh_fast(g_), og = sigmf(o_);
      cst = fg * cst + ig * gg;
      float h = og * tanh_fast(cst);
      unsigned short hh = f2h(h);
      h16[g * 64 + tid] = hh;
      __hip_atomic_store(&HexS[g * 64 + tid],
                         (unsigned int)hh | ((unsigned int)(tagBase + t + 1) << 16),
                         __ATOMIC_RELAXED, __HIP_MEMORY_SCOPE_AGENT);
      if (Hout) Hout[(b24 + t) * 256 + g * 64 + tid] = hh;
      if (lastOut && t == 23) lastOut[b * 256 + g * 64 + tid] = tanh_fast(h);
    }
    if (t == 23) break;
    if (tid < 256 && (tid >> 6) != g) {
      const unsigned int tag = (unsigned int)(tagBase + t + 1);
      unsigned int v;
      do {
        v = __hip_atomic_load(&HexS[tid], __ATOMIC_RELAXED, __HIP_MEMORY_SCOPE_AGENT);
      } while ((v >> 16) != tag);
      h16[tid] = (unsigned short)(v & 0xFFFFu);
    }
    __syncthreads();
  }
}

// ---------------- Z1 = H1f16 @ Wih1f16^T + biases (MFMA) ----------------
__global__ __launch_bounds__(256) void gemm_z1_mfma(
    const unsigned short* __restrict__ A, const unsigned short* __restrict__ B,
    const float* __restrict__ bih, const float* __restrict__ bhh,
    float* __restrict__ Z1) {
  __shared__ __align__(16) unsigned short As[128 * 32];
  __shared__ __align__(16) unsigned short Bs[128 * 32];
  const int K = 256;
  int nt = blockIdx.x;   // 0..7
  int mt = blockIdx.y;   // 0..5
  int m0 = mt * 128, n0 = nt * 128;
  int tid = threadIdx.x;
  int lane = tid & 63;
  int w = tid >> 6;
  int wm = (w >> 1) * 64, wn = (w & 1) * 64;
  int fr = lane & 15;
  int kg = lane >> 4;

  f32x4 acc[4][4] = {};
  const unsigned short* Ag = A + (size_t)m0 * K;
  const unsigned short* Bg = B + (size_t)n0 * K;

  for (int kk = 0; kk < 256; kk += 32) {
#pragma unroll
    for (int q = 0; q < 2; ++q) {
      int c = q * 256 + tid;
      int row = c >> 2;
      int ko = (c & 3) * 8;
      int cb = q * 256 + (tid & ~63);
      gload_lds16(&Ag[(size_t)row * K + kk + ko], &As[cb * 8]);
      gload_lds16(&Bg[(size_t)row * K + kk + ko], &Bs[cb * 8]);
    }
    __syncthreads();
    f16x8 aF[4], bF[4];
#pragma unroll
    for (int i = 0; i < 4; ++i)
      aF[i] = *(const f16x8*)&As[(wm + i * 16 + fr) * 32 + kg * 8];
#pragma unroll
    for (int i = 0; i < 4; ++i)
      bF[i] = *(const f16x8*)&Bs[(wn + i * 16 + fr) * 32 + kg * 8];
#pragma unroll
    for (int i = 0; i < 4; ++i)
#pragma unroll
      for (int j = 0; j < 4; ++j)
        acc[i][j] = __builtin_amdgcn_mfma_f32_16x16x32_f16(aF[i], bF[j], acc[i][j], 0, 0, 0);
    __syncthreads();
  }
  int mr = (lane >> 4) * 4;
#pragma unroll
  for (int j = 0; j < 4; ++j) {
    int n = n0 + wn + j * 16 + fr;
    float bias = bih[n] + bhh[n];
#pragma unroll
    for (int i = 0; i < 4; ++i) {
#pragma unroll
      for (int r = 0; r < 4; ++r) {
        int m = m0 + wm + i * 16 + mr + r;
        Z1[(size_t)m * 1024 + n] = acc[i][j][r] + bias;
      }
    }
  }
}

// ---------------- fc: out = last @ fc_W^T + fc_b ----------------
__global__ __launch_bounds__(256) void fc_kernel(
    const float* __restrict__ last, const float* __restrict__ fcW,
    const float* __restrict__ fcb, float* __restrict__ out) {
  __shared__ float ls[8][256];
  int tid = threadIdx.x;
  int o = blockIdx.x * 256 + tid;
  int b0 = blockIdx.y * 8;
  for (int i = tid; i < 2048; i += 256)
    ls[i >> 8][i & 255] = last[(b0 + (i >> 8)) * 256 + (i & 255)];
  __syncthreads();
  if (o < 8000) {
    float acc[8] = {};
    for (int k = 0; k < 256; k += 4) {
      float4 wv = *(const float4*)&fcW[(size_t)o * 256 + k];
#pragma unroll
      for (int b = 0; b < 8; ++b)
        acc[b] += wv.x * ls[b][k] + wv.y * ls[b][k + 1] + wv.z * ls[b][k + 2] + wv.w * ls[b][k + 3];
    }
    float bias = fcb[o];
#pragma unroll
    for (int b = 0; b < 8; ++b) out[(size_t)(b0 + b) * 8000 + o] = acc[b] + bias;
  }
}

// ---------------- launch ----------------
extern "C" void kernel_launch(void* const* d_in, const int* in_sizes, int n_in,
                              void* d_out, int out_size, void* d_ws, size_t ws_size,
                              hipStream_t stream) {
  const float* x    = (const float*)d_in[0];
  const int*   ei   = (const int*)d_in[1];
  const float* ed   = (const float*)d_in[2];
  const float* Wg   = (const float*)d_in[3];
  const float* bg   = (const float*)d_in[4];
  const float* Wih0 = (const float*)d_in[5];
  const float* Whh0 = (const float*)d_in[6];
  const float* bih0 = (const float*)d_in[7];
  const float* bhh0 = (const float*)d_in[8];
  const float* Wih1 = (const float*)d_in[9];
  const float* Whh1 = (const float*)d_in[10];
  const float* bih1 = (const float*)d_in[11];
  const float* bhh1 = (const float*)d_in[12];
  const float* fcW  = (const float*)d_in[13];
  const float* fcb  = (const float*)d_in[14];
  float* out = (float*)d_out;

  char* ws = (char*)d_ws;
  unsigned short* Gbf  = (unsigned short*)(ws);              // 24,576,000
  unsigned short* W0bf = (unsigned short*)(ws + 24576000);   // 32,768,000
  float* Zpart = (float*)(ws + 57344000);                    // 31,457,280
  uint2* WPG0  = (uint2*)(ws + 91947008);                    //    524,288
  uint2* WPG1  = (uint2*)(ws + 92471296);                    //    524,288
  unsigned short* W1h = (unsigned short*)(ws + 92995584);    //    524,288 (f16 Wih1)
  unsigned short* H1  = (unsigned short*)(ws + 94044160);    //    393,216 (f16 H1)
  float* Z1    = (float*)(ws + 94830592);                    //  3,145,728
  float* lastb = (float*)(ws + 97976320);                    //     32,768
  unsigned int* Hex0 = (unsigned int*)(ws + 98009088);       //     65,536
  unsigned int* Hex1 = (unsigned int*)(ws + 98074624);       //     65,536  (end ~98.1 MB)

  hipMemsetAsync(Hex0, 0, 131072, stream);   // zero both Hex buffers (tags invalid)
  fused_pre<<<2152, 1024, 0, stream>>>(x, ei, ed, Wg, bg, Gbf,
                                       Wih0, W0bf, Whh0, WPG0, Whh1, WPG1,
                                       Wih1, (unsigned short*)W1h);
  gemm_bt<<<dim3(8, 6, 10), 256, 0, stream>>>(Gbf, W0bf, Zpart);
  lstm_sync2<<<128, 1024, 0, stream>>>(nullptr, Zpart, bih0, bhh0, WPG0,
                                       Hex0, H1, nullptr, 0);
  gemm_z1_mfma<<<dim3(8, 6), 256, 0, stream>>>(H1, W1h, bih1, bhh1, Z1);
  lstm_sync2<<<128, 1024, 0, stream>>>(Z1, nullptr, nullptr, nullptr, WPG1,
                                       Hex1, nullptr, lastb, 100);
  fc_kernel<<<dim3(32, 4), 256, 0, stream>>>(lastb, fcW, fcb, out);
}